// Round 1
// baseline (1561.630 us; speedup 1.0000x reference)
//
#include <hip/hip_runtime.h>
#include <hip/hip_bf16.h>

// SplineConv (degree-1 B-spline, DIM=2, K=5, open), N=100000, E=1600000, 32->32.
// Strategy:
//   Kernel 1 (edge_kernel): weights cached in LDS as bf16 (25*32 rows, pitch 40
//     to stagger banks). 4 lanes per edge; each lane owns 8 output channels and
//     reads weights via ds_read_b128 (8 bf16 per read). Per edge:
//     y = sum_s basis_s * (x[col] @ W[idx_s]) computed in fp32, then 8 f32
//     atomicAdds per lane into d_out (used as the accumulator), degree counted
//     into d_ws.
//   Kernel 2 (finalize): out = out/max(deg,1) + x @ root_weight + bias.

#define NN   100000
#define EE   1600000
#define KTOT 25
#define PITCH 40   // bf16 elements per (k,i) row in LDS: 80B, staggers banks

__device__ __forceinline__ float bflo(unsigned d) {
    unsigned u = d << 16;
    return __builtin_bit_cast(float, u);
}
__device__ __forceinline__ float bfhi(unsigned d) {
    unsigned u = d & 0xffff0000u;
    return __builtin_bit_cast(float, u);
}

__global__ __launch_bounds__(512, 4)
void edge_kernel(const float* __restrict__ x,
                 const int* __restrict__ eidx,      // [2*E] int32: row=target, col=source
                 const float* __restrict__ pseudo,  // [E*2]
                 const float* __restrict__ weight,  // [25*32*32] fp32, k-major, then i, then o
                 float* __restrict__ acc,           // d_out as accumulator [N*32], pre-zeroed
                 float* __restrict__ deg)           // [N], pre-zeroed
{
    __shared__ __hip_bfloat16 wl[KTOT * 32 * PITCH];   // 64000 B

    // Stage weights (fp32 -> bf16 RNE), coalesced.
    for (int idx = threadIdx.x; idx < KTOT * 32 * 32; idx += 512) {
        int k = idx >> 10;
        int r = idx & 1023;
        int i = r >> 5;
        int o = r & 31;
        wl[(k * 32 + i) * PITCH + o] = __float2bfloat16(weight[idx]);
    }
    __syncthreads();

    const int sub = threadIdx.x & 3;            // which quarter of outputs
    const int og  = sub * 8;                    // output channel base (8 per lane)
    const int grpBase = (threadIdx.x & 63) & ~3; // wave-lane base of this edge's 4 lanes

    for (int base = blockIdx.x * 128; base < EE; base += gridDim.x * 128) {
        int e = base + (threadIdx.x >> 2);
        if (e < EE) {
            int row = eidx[e];
            int col = eidx[EE + e];

            // degree-1 spline basis, scale = K-1 = 4 (open)
            float p0 = pseudo[2 * e]     * 4.0f;
            float p1 = pseudo[2 * e + 1] * 4.0f;
            float l0f = floorf(p0), l1f = floorf(p1);
            float f0 = p0 - l0f, f1 = p1 - l1f;
            int l0 = (int)l0f, l1 = (int)l1f;
            int i0a = min(max(l0, 0), 4),     i0b = min(max(l0 + 1, 0), 4);
            int i1a = min(max(l1, 0), 4),     i1b = min(max(l1 + 1, 0), 4);
            float b0 = (1.0f - f0) * (1.0f - f1); int k0 = i0a + 5 * i1a; // s=(0,0)
            float b1 = (1.0f - f0) * f1;          int k1 = i0a + 5 * i1b; // s=(0,1)
            float b2 = f0 * (1.0f - f1);          int k2 = i0b + 5 * i1a; // s=(1,0)
            float b3 = f0 * f1;                   int k3 = i0b + 5 * i1b; // s=(1,1)

            // Each lane loads its 8 x-values (group of 4 lanes covers 32, coalesced).
            const float4* xp = (const float4*)(x + col * 32 + sub * 8);
            float4 xa = xp[0], xb = xp[1];
            float xs[8] = {xa.x, xa.y, xa.z, xa.w, xb.x, xb.y, xb.z, xb.w};

            const __hip_bfloat16* pa = &wl[k0 * 32 * PITCH + og];
            const __hip_bfloat16* pb = &wl[k1 * 32 * PITCH + og];
            const __hip_bfloat16* pc = &wl[k2 * 32 * PITCH + og];
            const __hip_bfloat16* pd = &wl[k3 * 32 * PITCH + og];

            float y[8] = {0, 0, 0, 0, 0, 0, 0, 0};

            #pragma unroll
            for (int i = 0; i < 32; ++i) {
                // broadcast x_i from the lane that holds it (within this edge's group)
                float xi = __shfl(xs[i & 7], grpBase + (i >> 3), 64);
                uint4 wA = *(const uint4*)(pa + i * PITCH);
                uint4 wB = *(const uint4*)(pb + i * PITCH);
                uint4 wC = *(const uint4*)(pc + i * PITCH);
                uint4 wD = *(const uint4*)(pd + i * PITCH);
                const unsigned* A = (const unsigned*)&wA;
                const unsigned* B = (const unsigned*)&wB;
                const unsigned* C = (const unsigned*)&wC;
                const unsigned* D = (const unsigned*)&wD;
                #pragma unroll
                for (int h = 0; h < 4; ++h) {
                    float wsL = b0 * bflo(A[h]) + b1 * bflo(B[h])
                              + b2 * bflo(C[h]) + b3 * bflo(D[h]);
                    float wsH = b0 * bfhi(A[h]) + b1 * bfhi(B[h])
                              + b2 * bfhi(C[h]) + b3 * bfhi(D[h]);
                    y[2 * h]     = fmaf(xi, wsL, y[2 * h]);
                    y[2 * h + 1] = fmaf(xi, wsH, y[2 * h + 1]);
                }
            }

            float* dst = acc + row * 32 + og;
            #pragma unroll
            for (int c = 0; c < 8; ++c) atomicAdd(dst + c, y[c]);
            if (sub == 0) atomicAdd(deg + row, 1.0f);
        }
    }
}

__global__ __launch_bounds__(256)
void finalize_kernel(const float* __restrict__ x,
                     const float* __restrict__ rootw,  // [32*32] i-major
                     const float* __restrict__ bias,   // [32]
                     const float* __restrict__ deg,    // [N]
                     float* __restrict__ out)          // [N*32] in/out
{
    __shared__ float rw[32 * 32];
    __shared__ float bs[32];
    for (int idx = threadIdx.x; idx < 1024; idx += 256) rw[idx] = rootw[idx];
    if (threadIdx.x < 32) bs[threadIdx.x] = bias[threadIdx.x];
    __syncthreads();

    int tid = blockIdx.x * 256 + threadIdx.x;
    int n = tid >> 5, o = tid & 31;
    if (n >= NN) return;

    float xv = x[n * 32 + o];
    int gb = (threadIdx.x & 63) & ~31;
    float v = 0.0f;
    #pragma unroll
    for (int i = 0; i < 32; ++i) {
        float xi = __shfl(xv, gb + i, 64);
        v = fmaf(xi, rw[i * 32 + o], v);
    }
    float d = fmaxf(deg[n], 1.0f);
    int idx = n * 32 + o;
    out[idx] = out[idx] / d + v + bs[o];
}

extern "C" void kernel_launch(void* const* d_in, const int* in_sizes, int n_in,
                              void* d_out, int out_size, void* d_ws, size_t ws_size,
                              hipStream_t stream) {
    const float* x      = (const float*)d_in[0];
    const int*   eidx   = (const int*)d_in[1];   // int32 on device (JAX x64 disabled)
    const float* pseudo = (const float*)d_in[2];
    const float* weight = (const float*)d_in[3];
    const float* rootw  = (const float*)d_in[4];
    const float* bias   = (const float*)d_in[5];
    float* out = (float*)d_out;
    float* deg = (float*)d_ws;

    hipMemsetAsync(out, 0, (size_t)NN * 32 * sizeof(float), stream);
    hipMemsetAsync(deg, 0, (size_t)NN * sizeof(float), stream);

    edge_kernel<<<1024, 512, 0, stream>>>(x, eidx, pseudo, weight, out, deg);
    finalize_kernel<<<(NN * 32 + 255) / 256, 256, 0, stream>>>(x, rootw, bias, deg, out);
}

// Round 2
// 1554.651 us; speedup vs baseline: 1.0045x; 1.0045x over previous
//
#include <hip/hip_runtime.h>
#include <hip/hip_bf16.h>

// SplineConv (degree-1 B-spline, DIM=2, K=5, open), N=100000, E=1600000, 32->32.
// R2: fix LDS bank-conflict degeneracy (k-stride was ≡0 mod 32 dwords -> all
//     lanes in a phase hit the same bank span; SQ_LDS_BANK_CONFLICT=1.35e8,
//     5.7x DS-pipe slowdown). New layout: KSTRIDE = 32*PITCH + 8 bf16 = 644
//     dwords ≡ 4 mod 32, so random k spreads lanes over all 8 16B span slots.
//     Also removed the 32 per-edge __shfl broadcasts (same DS pipe): each lane
//     loads the full 32-float x row (L1-broadcast across the edge's 4 lanes).

#define NN   100000
#define EE   1600000
#define KTOT 25
#define PITCH   40                  // bf16 per (k,i) row: 20 dwords
#define KSTRIDE (32 * PITCH + 8)    // 1288 bf16 = 644 dwords ≡ 4 (mod 32)

__device__ __forceinline__ float bflo(unsigned d) {
    unsigned u = d << 16;
    return __builtin_bit_cast(float, u);
}
__device__ __forceinline__ float bfhi(unsigned d) {
    unsigned u = d & 0xffff0000u;
    return __builtin_bit_cast(float, u);
}

__global__ __launch_bounds__(512, 4)
void edge_kernel(const float* __restrict__ x,
                 const int* __restrict__ eidx,      // [2*E] int32: row=target, col=source
                 const float* __restrict__ pseudo,  // [E*2]
                 const float* __restrict__ weight,  // [25*32*32] fp32 (k,i,o)
                 float* __restrict__ acc,           // d_out as accumulator [N*32], pre-zeroed
                 float* __restrict__ deg)           // [N], pre-zeroed
{
    __shared__ __hip_bfloat16 wl[KTOT * KSTRIDE];   // 64400 B -> still 2 blocks/CU

    for (int idx = threadIdx.x; idx < KTOT * 32 * 32; idx += 512) {
        int k = idx >> 10;
        int r = idx & 1023;
        int i = r >> 5;
        int o = r & 31;
        wl[k * KSTRIDE + i * PITCH + o] = __float2bfloat16(weight[idx]);
    }
    __syncthreads();

    const int sub = threadIdx.x & 3;   // quarter of output channels
    const int og  = sub * 8;           // output channel base (8 per lane)

    for (int base = blockIdx.x * 128; base < EE; base += gridDim.x * 128) {
        int e = base + (threadIdx.x >> 2);
        if (e < EE) {
            int row = eidx[e];
            int col = eidx[EE + e];

            // degree-1 spline basis, scale = K-1 = 4 (open)
            const float2 ps = *(const float2*)(pseudo + 2 * e);
            float p0 = ps.x * 4.0f;
            float p1 = ps.y * 4.0f;
            float l0f = floorf(p0), l1f = floorf(p1);
            float f0 = p0 - l0f, f1 = p1 - l1f;
            int l0 = (int)l0f, l1 = (int)l1f;
            int i0a = min(max(l0, 0), 4),     i0b = min(max(l0 + 1, 0), 4);
            int i1a = min(max(l1, 0), 4),     i1b = min(max(l1 + 1, 0), 4);
            float b0 = (1.0f - f0) * (1.0f - f1); int k0 = i0a + 5 * i1a;
            float b1 = (1.0f - f0) * f1;          int k1 = i0a + 5 * i1b;
            float b2 = f0 * (1.0f - f1);          int k2 = i0b + 5 * i1a;
            float b3 = f0 * f1;                   int k3 = i0b + 5 * i1b;

            // Full 32-float x row per lane (4 lanes share the edge -> L1 broadcast).
            const float4* xp = (const float4*)(x + col * 32);
            float X[32];
            #pragma unroll
            for (int q = 0; q < 8; ++q) {
                float4 v = xp[q];
                X[4 * q]     = v.x;
                X[4 * q + 1] = v.y;
                X[4 * q + 2] = v.z;
                X[4 * q + 3] = v.w;
            }

            const __hip_bfloat16* pa = &wl[k0 * KSTRIDE + og];
            const __hip_bfloat16* pb = &wl[k1 * KSTRIDE + og];
            const __hip_bfloat16* pc = &wl[k2 * KSTRIDE + og];
            const __hip_bfloat16* pd = &wl[k3 * KSTRIDE + og];

            float y[8] = {0, 0, 0, 0, 0, 0, 0, 0};

            #pragma unroll
            for (int i = 0; i < 32; ++i) {
                float xi = X[i];
                uint4 wA = *(const uint4*)(pa + i * PITCH);
                uint4 wB = *(const uint4*)(pb + i * PITCH);
                uint4 wC = *(const uint4*)(pc + i * PITCH);
                uint4 wD = *(const uint4*)(pd + i * PITCH);
                const unsigned* A = (const unsigned*)&wA;
                const unsigned* B = (const unsigned*)&wB;
                const unsigned* C = (const unsigned*)&wC;
                const unsigned* D = (const unsigned*)&wD;
                #pragma unroll
                for (int h = 0; h < 4; ++h) {
                    float wsL = b0 * bflo(A[h]) + b1 * bflo(B[h])
                              + b2 * bflo(C[h]) + b3 * bflo(D[h]);
                    float wsH = b0 * bfhi(A[h]) + b1 * bfhi(B[h])
                              + b2 * bfhi(C[h]) + b3 * bfhi(D[h]);
                    y[2 * h]     = fmaf(xi, wsL, y[2 * h]);
                    y[2 * h + 1] = fmaf(xi, wsH, y[2 * h + 1]);
                }
            }

            float* dst = acc + row * 32 + og;
            #pragma unroll
            for (int c = 0; c < 8; ++c) atomicAdd(dst + c, y[c]);
            if (sub == 0) atomicAdd(deg + row, 1.0f);
        }
    }
}

__global__ __launch_bounds__(256)
void finalize_kernel(const float* __restrict__ x,
                     const float* __restrict__ rootw,  // [32*32] i-major
                     const float* __restrict__ bias,   // [32]
                     const float* __restrict__ deg,    // [N]
                     float* __restrict__ out)          // [N*32] in/out
{
    __shared__ float rw[32 * 32];
    __shared__ float bs[32];
    for (int idx = threadIdx.x; idx < 1024; idx += 256) rw[idx] = rootw[idx];
    if (threadIdx.x < 32) bs[threadIdx.x] = bias[threadIdx.x];
    __syncthreads();

    int tid = blockIdx.x * 256 + threadIdx.x;
    int n = tid >> 5, o = tid & 31;
    if (n >= NN) return;

    float xv = x[n * 32 + o];
    int gb = (threadIdx.x & 63) & ~31;
    float v = 0.0f;
    #pragma unroll
    for (int i = 0; i < 32; ++i) {
        float xi = __shfl(xv, gb + i, 64);
        v = fmaf(xi, rw[i * 32 + o], v);
    }
    float d = fmaxf(deg[n], 1.0f);
    int idx = n * 32 + o;
    out[idx] = out[idx] / d + v + bs[o];
}

extern "C" void kernel_launch(void* const* d_in, const int* in_sizes, int n_in,
                              void* d_out, int out_size, void* d_ws, size_t ws_size,
                              hipStream_t stream) {
    const float* x      = (const float*)d_in[0];
    const int*   eidx   = (const int*)d_in[1];
    const float* pseudo = (const float*)d_in[2];
    const float* weight = (const float*)d_in[3];
    const float* rootw  = (const float*)d_in[4];
    const float* bias   = (const float*)d_in[5];
    float* out = (float*)d_out;
    float* deg = (float*)d_ws;

    hipMemsetAsync(out, 0, (size_t)NN * 32 * sizeof(float), stream);
    hipMemsetAsync(deg, 0, (size_t)NN * sizeof(float), stream);

    edge_kernel<<<1024, 512, 0, stream>>>(x, eidx, pseudo, weight, out, deg);
    finalize_kernel<<<(NN * 32 + 255) / 256, 256, 0, stream>>>(x, rootw, bias, deg, out);
}